// Round 19
// baseline (44.895 us; speedup 1.0000x reference)
//
#include <hip/hip_runtime.h>

#define HH 80
#define WW 80
#define IMG (HH * WW)             // 6400
#define NV ((HH - 1) * WW)        // 6320 vertical edge slots
#define NPTS (NV + HH * (WW - 1)) // 12640 edge slots per image
#define NPIX (2 * IMG)            // 12800
#define BIGF 1.0e10f
#define INVC 1.0e7f
#define EPSF 1e-8f
#define QSCALE 131072.0f          // 2^17 fixed point (exact-commutative sums)

// k_prep geometry: each set padded to 12800 slots = 50 blocks x 256 threads
#define SETPAD 12800
#define SBLOCKS (SETPAD / 256)    // 50 blocks per set
#define EXBLOCKS (4 * SBLOCKS)    // 200 extraction blocks
#define PXBLOCKS (NPIX / 256)     // 50 pixel blocks
#define PREPB (EXBLOCKS + PXBLOCKS) // 250

// k_minfin geometry (r11-exact tiling)
#define BLK 256                   // 4 waves
#define APT 8                     // A points per thread
#define ACHUNK (BLK * APT)        // 2048
#define ABLOCKS ((NPTS + ACHUNK - 1) / ACHUNK) // 7 worst case
#define NSLICE 32
#define DIRBLOCKS (ABLOCKS * NSLICE) // 224 blocks per dir (incl. early-outs)
#define MAXSLICE ((((NPTS + NSLICE - 1) / NSLICE) + 1) & ~1) // 396
#define MAXP2 (MAXSLICE / 2)      // 198 f32x2 pairs

// scalar ws layout (each contended counter on its own line)
#define CNT_STRIDE 32             // ints; cnt[set] at d_ws + set*128
#define PIX_OFF 512
#define DTICKET_OFF 640           // u32 per dir, 64 B apart: 640,704,768,832
#define DSUM_OFF 896              // u64[4]
#define FTICKET_OFF 960
#define SCALAR_BYTES 1024

typedef float f32x2 __attribute__((ext_vector_type(2)));

__device__ __forceinline__ long long wave_reduce_ll(long long v) {
#pragma unroll
  for (int o = 32; o > 0; o >>= 1) {
    int2 p = *(int2*)&v;
    p.x = __shfl_down(p.x, o, 64);
    p.y = __shfl_down(p.y, o, 64);
    v += *(long long*)&p;
  }
  return v;
}

// --------------------------------------------------------------- k_zero
__global__ void k_zero(unsigned int* __restrict__ w) {
  w[threadIdx.x] = 0u;   // 256 x 4 B = 1024 B (cnt, pix, tickets, sums)
}

// --------------------------------------------------------------- k_prep
// 250 blocks. minarr init + (blocks 0..199) zero-crossing extraction with
// block-aggregated atomic append (one atomicAdd per block, counters on
// separate cache lines) + (blocks 200..249) pixel loss in exact int64.
// Append ORDER is non-deterministic, but all consumers are order-invariant
// and exact (multiset min; int64 sums) -> output bitwise stable.
__global__ void __launch_bounds__(256) k_prep(
    const float* __restrict__ pred, const float* __restrict__ gt,
    float2* __restrict__ pts, float* __restrict__ minarr,
    int* __restrict__ cnt, unsigned long long* __restrict__ pix_i) {
  __shared__ int wc[4], wo[4];
  __shared__ long long rl[4];
  int tid = threadIdx.x, lane = tid & 63, wid = tid >> 6;
  int gtid = blockIdx.x * 256 + tid;

  if (gtid < 4 * NPTS) minarr[gtid] = BIGF;

  if (blockIdx.x < EXBLOCKS) {
    int set = blockIdx.x / SBLOCKS;
    int idx = (blockIdx.x % SBLOCKS) * 256 + tid;   // slot in [0, SETPAD)
    const float* s = (set < 2 ? pred : gt) + (set & 1) * IMG;
    float r = 0.f, c = 0.f;
    bool valid = false;
    if (idx < NPTS) {
      if (idx < NV) {
        int i = idx / WW, j = idx - i * WW;
        float v1 = s[i * WW + j], v2 = s[(i + 1) * WW + j];
        c = (float)j;
        if (v1 == 0.f)      { r = (float)i;       valid = true; }
        else if (v2 == 0.f) { r = (float)i + 1.f; valid = true; }
        else {
          r = (float)i + fabsf(v1) / (fabsf(v1) + fabsf(v2) + EPSF);
          valid = (v1 * v2 < 0.f);
        }
      } else {
        int t = idx - NV;
        int i = t / (WW - 1), j = t - i * (WW - 1);
        float h1 = s[i * WW + j], h2 = s[i * WW + j + 1];
        r = (float)i;
        if (h1 == 0.f)      { c = (float)j;       valid = true; }
        else if (h2 == 0.f) { c = (float)j + 1.f; valid = true; }
        else {
          c = (float)j + fabsf(h1) / (fabsf(h1) + fabsf(h2) + EPSF);
          valid = (h1 * h2 < 0.f);
        }
      }
    }
    unsigned long long mask = __ballot(valid);
    int nw = __popcll(mask);
    if (lane == 0) wc[wid] = nw;
    __syncthreads();
    if (tid == 0) {
      int t0 = wc[0], t1 = wc[1], t2 = wc[2], t3 = wc[3];
      int tot = t0 + t1 + t2 + t3;
      int base = tot ? atomicAdd(&cnt[set * CNT_STRIDE], tot) : 0;
      wo[0] = base; wo[1] = base + t0; wo[2] = base + t0 + t1;
      wo[3] = base + t0 + t1 + t2;
    }
    __syncthreads();
    if (valid) {
      int lpos = __popcll(mask & ((1ull << lane) - 1ull));
      pts[set * NPTS + wo[wid] + lpos] = make_float2(r, c);
    }
  } else {
    int p = (blockIdx.x - EXBLOCKS) * 256 + tid;
    float d = fabsf(pred[p] - gt[p]);
    long long q = (long long)(d * QSCALE + 0.5f);
    q = wave_reduce_ll(q);
    if (lane == 0) rl[wid] = q;
    __syncthreads();
    if (tid == 0)
      atomicAdd(pix_i, (unsigned long long)(rl[0] + rl[1] + rl[2] + rl[3]));
  }
}

// --------------------------------------------------------------- k_minfin
// dir 0: A=0 B=2 | 1: A=2 B=0 | 2: A=1 B=3 | 3: A=3 B=1  (A-sets dir-exclusive)
// Compute identical to r11 (LDS SoA staging, pk_fma + min3, TTAS atomicMin).
// FENCE-FREE lights-out: all cross-block data is device-scope-atomic-written
// (coherent point); __syncthreads drains vmcnt per wave (compiler emits
// s_waitcnt vmcnt(0) before s_barrier) -> relaxed per-dir ticket works.
// NO __threadfence (r8: per-block device fences at O(1000) blocks ~ 100 us).
__global__ void __launch_bounds__(BLK) k_minfin(
    const float2* __restrict__ pts, float* __restrict__ minarr,
    const int* __restrict__ cnt, const unsigned long long* __restrict__ pix_i,
    unsigned int* __restrict__ dticket, unsigned long long* __restrict__ dsum,
    unsigned int* __restrict__ fticket, float* __restrict__ out) {
  __shared__ f32x2 qx_s[MAXP2], qy_s[MAXP2], q2_s[MAXP2];
  __shared__ long long rl2[4];
  __shared__ int win_s;
  int tid = threadIdx.x, lane = tid & 63, wid = tid >> 6;

  int dir = blockIdx.z;
  int Aset = ((dir & 1) << 1) | (dir >> 1);
  int Bset = Aset ^ 2;
  int cntA = cnt[Aset * CNT_STRIDE], cntB = cnt[Bset * CNT_STRIDE];

  int abase0 = blockIdx.x * ACHUNK;
  int slicelen = (((cntB + NSLICE - 1) / NSLICE) + 1) & ~1;
  int b0 = blockIdx.y * slicelen;
  bool active = (abase0 < cntA) && (b0 < cntB);   // block-uniform

  if (active) {
    int n = min(slicelen, cntB - b0);
    int sn = (n + 1) & ~1;  // pad to even with a dummy far point
    for (int i = tid; i < sn; i += BLK) {
      float2 q = (i < n) ? pts[Bset * NPTS + b0 + i] : make_float2(INVC, INVC);
      ((float*)qx_s)[i] = q.x;
      ((float*)qy_s)[i] = q.y;
      ((float*)q2_s)[i] = fmaf(q.x, q.x, q.y * q.y);
    }
    __syncthreads();

    int abase = abase0 + tid;
    f32x2 nxv[APT], nyv[APT];
    float p2v[APT], m[APT];
#pragma unroll
    for (int i = 0; i < APT; ++i) {
      int a = abase + i * BLK;
      float2 p = (a < cntA) ? pts[Aset * NPTS + a] : make_float2(0.f, 0.f);
      float nx = -2.f * p.x, ny = -2.f * p.y;
      nxv[i].x = nx; nxv[i].y = nx;
      nyv[i].x = ny; nyv[i].y = ny;
      p2v[i] = fmaf(p.x, p.x, p.y * p.y);
      m[i] = 3.0e38f;
    }

    int np2 = sn >> 1;
#pragma unroll 2
    for (int p = 0; p < np2; ++p) {
      f32x2 qx = qx_s[p], qy = qy_s[p], q2 = q2_s[p];
#pragma unroll
      for (int i = 0; i < APT; ++i) {
        f32x2 u = __builtin_elementwise_fma(
            nyv[i], qy, __builtin_elementwise_fma(nxv[i], qx, q2));
        m[i] = fminf(fminf(u.x, u.y), m[i]);   // -> v_min3_f32
      }
    }

#pragma unroll
    for (int i = 0; i < APT; ++i) {
      int a = abase + i * BLK;
      if (a < cntA) {
        float d2 = fmaxf(m[i] + p2v[i], 0.f);
        unsigned int mine = __float_as_uint(d2);
        unsigned int* addr = (unsigned int*)&minarr[Aset * NPTS + a];
        unsigned int cur = __hip_atomic_load(addr, __ATOMIC_RELAXED,
                                             __HIP_MEMORY_SCOPE_AGENT);
        // non-negative floats order as uint bit patterns; min is order-exact
        if (mine < cur) atomicMin(addr, mine);
      }
    }
  }

  // ---- per-dir lights-out (all DIRBLOCKS blocks of this dir arrive here)
  __syncthreads();   // drains each wave's vmcnt (atomicMins complete)
  if (tid == 0) {
    unsigned int t = __hip_atomic_fetch_add(
        &dticket[dir * 16], 1u, __ATOMIC_RELAXED, __HIP_MEMORY_SCOPE_AGENT);
    win_s = (t == DIRBLOCKS - 1) ? 1 : 0;
  }
  __syncthreads();
  if (!win_s) return;

  // last block of this dir: exact int64 sum of sqrt(min d2) over its A-set.
  // minarr was only ever written via device-scope atomics -> agent-scope
  // atomic loads read the coherent point (no stale L1/L2 copies exist).
  long long ls = 0;
  for (int i = tid; i < cntA; i += BLK) {
    unsigned int ub = __hip_atomic_load(
        (unsigned int*)&minarr[Aset * NPTS + i], __ATOMIC_RELAXED,
        __HIP_MEMORY_SCOPE_AGENT);
    float d2 = __uint_as_float(ub);
    ls += (long long)(sqrtf(d2) * QSCALE + 0.5f);
  }
  ls = wave_reduce_ll(ls);
  if (lane == 0) rl2[wid] = ls;
  __syncthreads();
  if (tid == 0) {
    long long tot = rl2[0] + rl2[1] + rl2[2] + rl2[3];
    __hip_atomic_store(&dsum[Aset], (unsigned long long)tot,
                       __ATOMIC_RELAXED, __HIP_MEMORY_SCOPE_AGENT);
    asm volatile("s_waitcnt vmcnt(0)" ::: "memory");  // dsum at coherent point
    unsigned int t = __hip_atomic_fetch_add(fticket, 1u, __ATOMIC_RELAXED,
                                            __HIP_MEMORY_SCOPE_AGENT);
    if (t == 3u) {   // all four dir-sums stored
      const float iq = 1.0f / QSCALE;
      float ss[4];
      for (int k = 0; k < 4; ++k) {
        unsigned long long v = __hip_atomic_load(&dsum[k], __ATOMIC_RELAXED,
                                                 __HIP_MEMORY_SCOPE_AGENT);
        ss[k] = (float)(long long)v * iq;
      }
      float n0 = fmaxf((float)cnt[0 * CNT_STRIDE], 1.f);
      float n1 = fmaxf((float)cnt[1 * CNT_STRIDE], 1.f);
      float n2 = fmaxf((float)cnt[2 * CNT_STRIDE], 1.f);
      float n3 = fmaxf((float)cnt[3 * CNT_STRIDE], 1.f);
      float ch0 = -ss[0] / n0 + ss[2] / n2;
      float ch1 = -ss[1] / n1 + ss[3] / n3;
      out[0] = (float)(long long)(*pix_i) * iq / (float)NPIX;
      out[1] = 0.5f * (ch0 + ch1);
    }
  }
}

extern "C" void kernel_launch(void* const* d_in, const int* in_sizes, int n_in,
                              void* d_out, int out_size, void* d_ws, size_t ws_size,
                              hipStream_t stream) {
  const float* pred = (const float*)d_in[0];
  const float* gt   = (const float*)d_in[1];
  float* out = (float*)d_out;

  // ws: [0..1023] scalars (zeroed by k_zero) | 4*NPTS float2 pts | 4*NPTS float mins
  int* cnt = (int*)d_ws;                                                // lines @0,128,256,384
  unsigned long long* pix_i = (unsigned long long*)((char*)d_ws + PIX_OFF);
  unsigned int* dticket = (unsigned int*)((char*)d_ws + DTICKET_OFF);   // [dir*16]
  unsigned long long* dsum = (unsigned long long*)((char*)d_ws + DSUM_OFF);
  unsigned int* fticket = (unsigned int*)((char*)d_ws + FTICKET_OFF);
  float2* pts   = (float2*)((char*)d_ws + SCALAR_BYTES);
  float* minarr = (float*)((char*)d_ws + SCALAR_BYTES + sizeof(float2) * 4 * NPTS);

  k_zero<<<1, 256, 0, stream>>>((unsigned int*)d_ws);
  k_prep<<<PREPB, 256, 0, stream>>>(pred, gt, pts, minarr, cnt, pix_i);
  k_minfin<<<dim3(ABLOCKS, NSLICE, 4), BLK, 0, stream>>>(
      pts, minarr, cnt, pix_i, dticket, dsum, fticket, out);
}